// Round 3
// baseline (1597.382 us; speedup 1.0000x reference)
//
#include <hip/hip_runtime.h>

// Autoregressive masked net sampler.
//  - output col i == sampling-time x[:,i]  (masks: out i depends on spins < i only)
//  - spin blocks of KB=8: history part = dense GEMM (MFMA f16), intra-block part
//    sequential per-row (rows independent -> no grid sync).
// R4: single-wave WGs, scalar dot8 phases -> 123us/dispatch, VALUBusy 20%, occ 10.7%.
// R5: 2-way k-split doubled waves; counters matched (occ 21%, VALU 33%) but time only
//     -7% -> wall == per-WG serial chain latency; extra instructions ate the TLP gain.
// R7 (this): shrink the chain itself: every intra-block phase is a 20xKx16 GEMM ->
//     do it with mfma_f32_16x16x32_f16 (2 out-tiles, K<=160). Phase cost drops from
//     ~200 VALU + 31-deep dep chains to ~10 MFMA + 8 sigmoids. z6 scatter = 1 MFMA/t
//     into a persistent f32x4; z6 history moved to a separate MFMA kernel (gemm_z6).
//     BT back to 16 (fixes R5's Zg 64B-line split overfetch). Weight copies padded to
//     32 ch/spin (Wp2/W1p2/W6b) so tile1 rows 20..31 are zeros; K roundup reads
//     zero-weights x zero-activations => exact.

#define NS   64          // spins
#define HC   20          // hidden channels per spin
#define HTOT 1280        // NS*HC
#define NB   16384       // batch
#define KB   8           // spins per block (8 blocks)
#define BT   16          // batch rows per seq workgroup (MFMA N-tile)

typedef _Float16 f16;
typedef _Float16 f16x4 __attribute__((ext_vector_type(4)));
typedef _Float16 f16x8 __attribute__((ext_vector_type(8)));
typedef float f32x4 __attribute__((ext_vector_type(4)));

static __device__ __forceinline__ float sigm(float z) {
  return __builtin_amdgcn_rcpf(1.0f + __expf(-z));
}

// ---------------------------------------------------------------------------
// prep: build masked, spin-major-permuted f16 weights.
//  Wp  [L][cp][xp]            cp=j_o*20+ch_o, xp=j_i*20+ch_i, mask j_i<=j_o (gemm A)
//  Wp2 [L][spin][32][xp]      same rows, ch padded 20->32 with zeros (seq MFMA A)
//  W1p2[spin][32][64]         mask j_i<spin (exclusive), ch-padded (seq L1 MFMA A)
//  W6b [m][t][16][32]         intra-block W6 tile: row tp, col k: W6[I+tp][(I+t)*20+k]
//                             masked (t<=tp, tp<8, k<20) else 0 (z6 MFMA A)
//  W6pp[m][16][HTOT]          W6 masked rows I..I+7 padded to 16 rows (gemm_z6 A)
// ---------------------------------------------------------------------------
__global__ __launch_bounds__(256) void prep(
    const float* __restrict__ W1, const float* __restrict__ W2,
    const float* __restrict__ W3, const float* __restrict__ W4,
    const float* __restrict__ W5, const float* __restrict__ W6,
    f16* __restrict__ Wp, f16* __restrict__ Wp2, f16* __restrict__ W1p2,
    f16* __restrict__ W6b, f16* __restrict__ W6pp) {
  __shared__ float row[HTOT];
  int bid = blockIdx.x;
  if (bid < 4 * HTOT) {
    int L = bid / HTOT, cp = bid % HTOT;
    int j_o = cp / HC, ch_o = cp % HC;
    const float* Wsrc = (L == 0) ? W2 : (L == 1) ? W3 : (L == 2) ? W4 : W5;
    const float* src = Wsrc + (size_t)(ch_o * NS + j_o) * HTOT;
    for (int k = threadIdx.x; k < HTOT; k += 256) row[k] = src[k];
    __syncthreads();
    f16* dst  = Wp + (size_t)bid * HTOT;
    f16* dst2 = Wp2 + ((size_t)(L * NS + j_o) * 32 + ch_o) * HTOT;
    for (int xp = threadIdx.x; xp < HTOT; xp += 256) {
      int j_i = xp / HC, ch_i = xp % HC;
      f16 v = (f16)((j_i <= j_o) ? row[ch_i * NS + j_i] : 0.0f);
      dst[xp] = v;
      dst2[xp] = v;
    }
    if (ch_o < 12) {
      f16* dz = Wp2 + ((size_t)(L * NS + j_o) * 32 + 20 + ch_o) * HTOT;
      for (int xp = threadIdx.x; xp < HTOT; xp += 256) dz[xp] = (f16)0.0f;
    }
  } else if (bid < 4 * HTOT + NS) {
    int j_o = bid - 4 * HTOT;
    for (int idx = threadIdx.x; idx < 32 * 64; idx += 256) {
      int ch = idx >> 6, c = idx & 63;
      float v = (ch < HC && c < j_o) ? W1[((size_t)ch * NS + j_o) * NS + c] : 0.0f;
      W1p2[(size_t)(j_o * 32 + ch) * 64 + c] = (f16)v;
    }
  } else if (bid < 4 * HTOT + NS + 8) {
    int m = bid - (4 * HTOT + NS);
    int I = m * KB;
    for (int idx = threadIdx.x; idx < 8 * 16 * 32; idx += 256) {
      int t = idx >> 9, tp = (idx >> 5) & 15, k = idx & 31;
      float v = (tp < 8 && k < HC && t <= tp)
                    ? W6[(size_t)(I + tp) * HTOT + k * NS + (I + t)]
                    : 0.0f;
      W6b[(size_t)((m * 8 + t) * 16 + tp) * 32 + k] = (f16)v;
    }
  } else {
    int m = bid - (4 * HTOT + NS + 8);
    int I = m * KB;
    for (int idx = threadIdx.x; idx < 16 * HTOT; idx += 256) {
      int tp = idx / HTOT, xp = idx % HTOT;
      int j_i = xp / HC, ch_i = xp % HC;
      float v = (tp < 8 && j_i <= I + tp)
                    ? W6[(size_t)(I + tp) * HTOT + ch_i * NS + j_i]
                    : 0.0f;
      W6pp[(size_t)(m * 16 + tp) * HTOT + xp] = (f16)v;
    }
  }
}

// ---------------------------------------------------------------------------
// gemm_block_mfma: history part for layers 2..5 of block starting at spin I.
//   Zg[L][c][b] = sum_{k < 20I} Wp[L][20I + c][k] * AH[L][k][b],  c = 0..159
// MFMA f32_16x16x32_f16; AH [L][g=k/8][b][e=k%8] is the raw B-fragment layout.
// ---------------------------------------------------------------------------
__global__ __launch_bounds__(256) void gemm_block_mfma(
    const f16* __restrict__ Wp, const f16* __restrict__ AH,
    float* __restrict__ Zg, int I, int BS) {
  const int L = blockIdx.y;
  const int w = threadIdx.x >> 6;
  const int wm = w & 1, wn = w >> 1;
  const int l15 = threadIdx.x & 15;
  const int quad = (threadIdx.x & 63) >> 4;
  const int b0 = blockIdx.x * 64 + wn * 32;
  const int G32 = (HC * I) >> 5;

  f32x4 acc[5][2];
#pragma unroll
  for (int mt = 0; mt < 5; ++mt) {
    acc[mt][0] = (f32x4){0.f, 0.f, 0.f, 0.f};
    acc[mt][1] = (f32x4){0.f, 0.f, 0.f, 0.f};
  }

  const f16* aptr = Wp + (size_t)(L * HTOT + HC * I + wm * 80 + l15) * HTOT + quad * 8;
  const f16* bptr = AH + ((size_t)(L * 160 + quad) * BS + b0 + l15) * 8;

  for (int ks = 0; ks < G32; ++ks) {
    f16x8 bf0 = *(const f16x8*)(bptr);
    f16x8 bf1 = *(const f16x8*)(bptr + 128);
    f16x8 af[5];
#pragma unroll
    for (int mt = 0; mt < 5; ++mt)
      af[mt] = *(const f16x8*)(aptr + (size_t)(mt * 16) * HTOT);
#pragma unroll
    for (int mt = 0; mt < 5; ++mt) {
      acc[mt][0] = __builtin_amdgcn_mfma_f32_16x16x32_f16(af[mt], bf0, acc[mt][0], 0, 0, 0);
      acc[mt][1] = __builtin_amdgcn_mfma_f32_16x16x32_f16(af[mt], bf1, acc[mt][1], 0, 0, 0);
    }
    aptr += 32;
    bptr += (size_t)4 * BS * 8;
  }

#pragma unroll
  for (int mt = 0; mt < 5; ++mt)
#pragma unroll
    for (int nt = 0; nt < 2; ++nt)
#pragma unroll
      for (int r = 0; r < 4; ++r) {
        int c = wm * 80 + mt * 16 + quad * 4 + r;
        int b = b0 + nt * 16 + l15;
        Zg[(size_t)(L * 160 + c) * BS + b] = acc[mt][nt][r];
      }
}

// ---------------------------------------------------------------------------
// gemm_z6: layer-6 history part.  Zg6[tp][b] = sum_{k<20I} W6pp[m][tp][k]*AH[4][k][b]
// 16 rows (8 real), 4 waves x 16 batch cols per block.
// ---------------------------------------------------------------------------
__global__ __launch_bounds__(256) void gemm_z6(
    const f16* __restrict__ W6pp, const f16* __restrict__ AH,
    float* __restrict__ Zg6, int I, int BS) {
  const int w = threadIdx.x >> 6;
  const int l15 = threadIdx.x & 15;
  const int quad = (threadIdx.x & 63) >> 4;
  const int b0 = blockIdx.x * 64 + w * 16;
  const int m = I >> 3;
  const int G32 = (HC * I) >> 5;

  f32x4 acc = (f32x4){0.f, 0.f, 0.f, 0.f};
  const f16* aptr = W6pp + (size_t)(m * 16 + l15) * HTOT + quad * 8;
  const f16* bptr = AH + ((size_t)(4 * 160 + quad) * BS + b0 + l15) * 8;
  for (int ks = 0; ks < G32; ++ks) {
    f16x8 bf = *(const f16x8*)bptr;
    f16x8 af = *(const f16x8*)aptr;
    acc = __builtin_amdgcn_mfma_f32_16x16x32_f16(af, bf, acc, 0, 0, 0);
    aptr += 32;
    bptr += (size_t)4 * BS * 8;
  }
#pragma unroll
  for (int r = 0; r < 4; ++r)
    Zg6[(size_t)(quad * 4 + r) * BS + b0 + l15] = acc[r];
}

// ---------------------------------------------------------------------------
// seq_block v5 (MFMA phases): 1 wave, BT=16 batch rows = MFMA N dim.
// Per t: L1 = 2 tiles x <=2 K-steps; layers 2..5 = 2 tiles x <=5 K-steps each,
// init from Zg; z6 = 1 MFMA/t into persistent acc6 (init from Zg6). Fragment
// mappings mirror gemm_block_mfma (A: row=l15,k=quad*8; B: col=l15; C: col=l15,
// row=quad*4+reg). All K roundup slop = zero-weights x zero-activations.
// ---------------------------------------------------------------------------
__global__ __launch_bounds__(64) void seq_block(
    const f16* __restrict__ Wp2, const f16* __restrict__ W1p2,
    const f16* __restrict__ W6b, f16* __restrict__ AH,
    const float* __restrict__ Zg, const float* __restrict__ Zg6,
    f16* __restrict__ s_ws, const float* __restrict__ u,
    float* __restrict__ outp, int I, int BS, int b0) {
  __shared__ __align__(16) f16 aL[5][BT][184];   // 29440 B (184: 2-way-free banks, fits t*20+31)
  __shared__ __align__(16) f16 sL[BT][72];       // 2304 B -> 31744 B total

  const int lane = threadIdx.x;
  const int l15 = lane & 15;            // MFMA col = batch row in WG
  const int quad = lane >> 4;           // MFMA k-group / C row-group
  const int m = I >> 3;
  const int bcol = blockIdx.x * BT + l15;
  const int bg = b0 + bcol;

  // zero LDS (masked-weight / K-pad tails must read as 0)
  {
    f16x8 z = {};
    f16x8* pa = (f16x8*)&aL[0][0][0];
    for (int k = lane; k < (5 * BT * 184) / 8; k += 64) pa[k] = z;
    f16x8* ps = (f16x8*)&sL[0][0];
    for (int k = lane; k < (BT * 72) / 8; k += 64) ps[k] = z;
  }
  __syncthreads();

  // load sampled-bit history j < I
  for (int c8 = quad; c8 < (I >> 3); c8 += 4) {
    f16x8 v = *(const f16x8*)(s_ws + (size_t)(blockIdx.x * BT + l15) * NS + c8 * 8);
    *(f16x8*)&sL[l15][c8 * 8] = v;
  }

  // z6 accumulator: C rows = tp (quad*4+r), cols = batch (l15); init from history GEMM
  f32x4 acc6;
#pragma unroll
  for (int r = 0; r < 4; ++r)
    acc6[r] = Zg6[(size_t)(quad * 4 + r) * BS + bcol];
  __syncthreads();

  for (int t = 0; t < KB; ++t) {
    const int i = I + t;

    // ---- layer 1: z[32ch x 16b] = W1p2[i] (32x64) . sL (64x16), K=ceil(i/32)*32 ----
    {
      f32x4 z0 = (f32x4){0.f, 0.f, 0.f, 0.f};
      f32x4 z1 = (f32x4){0.f, 0.f, 0.f, 0.f};
      const int KS1 = (i + 31) >> 5;
      const f16* w0 = W1p2 + ((size_t)i * 32 + l15) * 64 + quad * 8;
      for (int ks = 0; ks < KS1; ++ks) {
        f16x8 bf = *(const f16x8*)&sL[l15][quad * 8 + 32 * ks];
        f16x8 a0 = *(const f16x8*)(w0 + 32 * ks);
        f16x8 a1 = *(const f16x8*)(w0 + 16 * 64 + 32 * ks);
        z0 = __builtin_amdgcn_mfma_f32_16x16x32_f16(a0, bf, z0, 0, 0, 0);
        z1 = __builtin_amdgcn_mfma_f32_16x16x32_f16(a1, bf, z1, 0, 0, 0);
      }
      f16x4 o0;
#pragma unroll
      for (int r = 0; r < 4; ++r) o0[r] = (f16)sigm(z0[r]);
      *(f16x4*)&aL[0][l15][t * HC + quad * 4] = o0;
      if (quad == 0) {
        f16x4 o1;
#pragma unroll
        for (int r = 0; r < 4; ++r) o1[r] = (f16)sigm(z1[r]);
        *(f16x4*)&aL[0][l15][t * HC + 16] = o1;
      }
    }
    __syncthreads();

    // ---- layers 2..5: z = Zg-init + Wp2[L][i] (32xK) . aL[L] (Kx16) ----
    const int KS = (HC * (t + 1) + 31) >> 5;
    for (int L = 0; L < 4; ++L) {
      f32x4 z0, z1;
#pragma unroll
      for (int r = 0; r < 4; ++r) {
        z0[r] = Zg[(size_t)(L * 160 + t * HC + quad * 4 + r) * BS + bcol];
        z1[r] = 0.f;
      }
      if (quad == 0) {
#pragma unroll
        for (int r = 0; r < 4; ++r)
          z1[r] = Zg[(size_t)(L * 160 + t * HC + 16 + r) * BS + bcol];
      }
      const f16* wb = Wp2 + ((size_t)(L * NS + i) * 32) * HTOT + HC * I;
      for (int ks = 0; ks < KS; ++ks) {
        f16x8 bf = *(const f16x8*)&aL[L][l15][quad * 8 + 32 * ks];
        f16x8 a0 = *(const f16x8*)(wb + (size_t)l15 * HTOT + quad * 8 + 32 * ks);
        f16x8 a1 = *(const f16x8*)(wb + (size_t)(16 + l15) * HTOT + quad * 8 + 32 * ks);
        z0 = __builtin_amdgcn_mfma_f32_16x16x32_f16(a0, bf, z0, 0, 0, 0);
        z1 = __builtin_amdgcn_mfma_f32_16x16x32_f16(a1, bf, z1, 0, 0, 0);
      }
      f16x4 o0;
#pragma unroll
      for (int r = 0; r < 4; ++r) o0[r] = (f16)sigm(z0[r]);
      *(f16x4*)&aL[L + 1][l15][t * HC + quad * 4] = o0;
      if (quad == 0) {
        f16x4 o1;
#pragma unroll
        for (int r = 0; r < 4; ++r) o1[r] = (f16)sigm(z1[r]);
        *(f16x4*)&aL[L + 1][l15][t * HC + 16] = o1;
      }
      __syncthreads();
    }

    // ---- z6: one MFMA accumulating a5(spin i) into all tp rows (W6b masks tp<t) ----
    {
      f16x8 b5 = *(const f16x8*)&aL[4][l15][t * HC + quad * 8];
      f16x8 a6 = *(const f16x8*)(W6b + ((size_t)((m * 8 + t) * 16) + l15) * 32 + quad * 8);
      acc6 = __builtin_amdgcn_mfma_f32_16x16x32_f16(a6, b5, acc6, 0, 0, 0);
      if (quad == (t >> 2)) {
        int r3 = t & 3;
        float v = r3 == 0 ? acc6[0] : r3 == 1 ? acc6[1] : r3 == 2 ? acc6[2] : acc6[3];
        float x = sigm(v);
        outp[(size_t)bg * NS + i] = x;  // final output col i == sampling-time x
        float uu = u[(size_t)i * NB + bg];
        sL[l15][i] = (f16)((x >= uu) ? 1.0f : -1.0f);
      }
    }
    __syncthreads();
  }

  // ---- bulk writeout: block activations -> global AH ([L][g][b][e]), s bits ----
  for (int w = lane; w < 5 * 20 * BT; w += 64) {
    int rr = w & 15;
    int q = w >> 4;            // 0..99
    int L = q / 20, x8 = q % 20;
    f16x8 v = *(const f16x8*)&aL[L][rr][x8 * 8];
    int gg = ((HC * I) >> 3) + x8;
    *(f16x8*)(AH + ((size_t)(L * 160 + gg) * BS + blockIdx.x * BT + rr) * 8) = v;
  }
  if (lane < BT) {
    *(f16x8*)(s_ws + (size_t)(blockIdx.x * BT + lane) * NS + I) =
        *(const f16x8*)&sL[lane][I];
  }
}

// ---------------------------------------------------------------------------
extern "C" void kernel_launch(void* const* d_in, const int* in_sizes, int n_in,
                              void* d_out, int out_size, void* d_ws, size_t ws_size,
                              hipStream_t stream) {
  (void)in_sizes; (void)n_in; (void)out_size;
  const float* u  = (const float*)d_in[1];
  const float* W1 = (const float*)d_in[2];
  const float* W2 = (const float*)d_in[3];
  const float* W3 = (const float*)d_in[4];
  const float* W4 = (const float*)d_in[5];
  const float* W5 = (const float*)d_in[6];
  const float* W6 = (const float*)d_in[7];
  float* outp = (float*)d_out;

  const size_t wpEls   = (size_t)4 * HTOT * HTOT;       // gemm A
  const size_t wp2Els  = (size_t)4 * NS * 32 * HTOT;    // seq phase A (ch-padded)
  const size_t w1Els   = (size_t)NS * 32 * 64;          // seq L1 A
  const size_t w6bEls  = (size_t)8 * 8 * 16 * 32;       // seq z6 A
  const size_t w6ppEls = (size_t)8 * 16 * HTOT;         // gemm_z6 A
  const size_t wEls = wpEls + wp2Els + w1Els + w6bEls + w6ppEls;
  const size_t wBytes = wEls * sizeof(f16);

  // per-batch-row workspace: AH 5*160*8*2 + Zg 4*160*4 + Zg6 16*4 + s_ws 64*2
  size_t rem = (ws_size > wBytes + 4096) ? (ws_size - wBytes - 4096) : 0;
  long long bs = (long long)(rem / 15552);
  bs = (bs / 64) * 64;
  if (bs > NB) bs = NB;
  if (bs < 64) bs = 64;
  const int BS = (int)bs;

  f16* Wp    = (f16*)d_ws;
  f16* Wp2   = Wp + wpEls;
  f16* W1p2  = Wp2 + wp2Els;
  f16* W6b   = W1p2 + w1Els;
  f16* W6pp  = W6b + w6bEls;
  f16* AH    = W6pp + w6ppEls;
  float* Zg  = (float*)(AH + (size_t)5 * 160 * BS * 8);
  float* Zg6 = Zg + (size_t)4 * 160 * BS;
  f16* s_ws  = (f16*)(Zg6 + (size_t)16 * BS);

  prep<<<dim3(4 * HTOT + NS + 16), dim3(256), 0, stream>>>(
      W1, W2, W3, W4, W5, W6, Wp, Wp2, W1p2, W6b, W6pp);

  for (int c0 = 0; c0 < NB; c0 += BS) {
    int nr = NB - c0; if (nr > BS) nr = BS;
    for (int m = 0; m < NS / KB; ++m) {
      const int I = m * KB;
      gemm_block_mfma<<<dim3(nr / 64, 4), dim3(256), 0, stream>>>(Wp, AH, Zg, I, BS);
      gemm_z6<<<dim3(nr / 64), dim3(256), 0, stream>>>(W6pp, AH, Zg6, I, BS);
      seq_block<<<dim3(nr / BT), dim3(64), 0, stream>>>(
          Wp2, W1p2, W6b, AH, Zg, Zg6, s_ws, u, outp, I, BS, c0);
    }
  }
}

// Round 4
// 1352.141 us; speedup vs baseline: 1.1814x; 1.1814x over previous
//
#include <hip/hip_runtime.h>

// Autoregressive masked net sampler.
//  - output col i == sampling-time x[:,i]  (masks: out i depends on spins < i only)
//  - spin blocks of KB=8: history part = dense GEMM (MFMA f16), intra-block part
//    sequential per-row (rows independent -> no grid sync).
// R4: scalar dot8 seq -> 123us, VALU-latency bound. R5: k-split occupancy: null.
// R7: seq phases -> MFMA (seq 115->~36us) BUT z6 split into 16 serial dispatches and
//     gemm_block_mfma revealed as top kernel: 98.6us, FETCH == AH stream exactly
//     (745 GB/s, 12% of peak), MfmaUtil 8%. 6700 cy/K-iter => NOT bandwidth: the
//     A-operand loads (lane stride = HTOT*2 = 2560 B) touch 64 cache lines per
//     instruction -> TA serialization, unhidable at 2 waves/SIMD.
// R8 (this): pre-swizzle ALL MFMA A-operands into fragment order [tile][ks][lane][8]
//     (WpT/WsT/W1T/W6bT/W6T) so every A-load is one coalesced 1KB wave-read; merge
//     gemm_z6 into gemm_hist as blockIdx.y==4 (removes 16 serial dispatches).

#define NS   64          // spins
#define HC   20          // hidden channels per spin
#define HTOT 1280        // NS*HC
#define NB   16384       // batch
#define KB   8           // spins per block (8 blocks)
#define BT   16          // batch rows per seq workgroup (MFMA N-tile)

typedef _Float16 f16;
typedef _Float16 f16x4 __attribute__((ext_vector_type(4)));
typedef _Float16 f16x8 __attribute__((ext_vector_type(8)));
typedef float f32x4 __attribute__((ext_vector_type(4)));

static __device__ __forceinline__ float sigm(float z) {
  return __builtin_amdgcn_rcpf(1.0f + __expf(-z));
}

// ---------------------------------------------------------------------------
// prep: build masked f16 weights, pre-swizzled to MFMA A-fragment order.
// Fragment order: lane = quad*16 + row15, elems 8; col = ks*32 + quad*8 + e.
//  WpT [L][rt=row/16][ks=0..39][512]   row=j_o*20+ch_o, mask j_i<=j_o (hist A)
//  WsT [L][i][tile=ch/16][ks=0..4][512] cols rel to HC*(i&~7), ch padded ->32 (seq A)
//  W1T [i][tile][ks=0..1][512]          cols = spins, mask c<i (seq L1 A)
//  W6bT[m*8+t][512]                     16 tp rows x 32 k, mask t<=tp,k<20 (z6 MFMA A)
//  W6T [m][ks=0..39][512]               16 tp rows (8 real), mask j_i<=I+tp (z6 hist A)
// ---------------------------------------------------------------------------
__global__ __launch_bounds__(256) void prep(
    const float* __restrict__ W1, const float* __restrict__ W2,
    const float* __restrict__ W3, const float* __restrict__ W4,
    const float* __restrict__ W5, const float* __restrict__ W6,
    f16* __restrict__ WpT, f16* __restrict__ WsT, f16* __restrict__ W1T,
    f16* __restrict__ W6bT, f16* __restrict__ W6T) {
  __shared__ float row[HTOT];
  int bid = blockIdx.x;
  if (bid < 4 * HTOT) {
    int L = bid / HTOT, cp = bid % HTOT;
    int j_o = cp / HC, ch_o = cp % HC;
    const float* Wsrc = (L == 0) ? W2 : (L == 1) ? W3 : (L == 2) ? W4 : W5;
    const float* src = Wsrc + (size_t)(ch_o * NS + j_o) * HTOT;
    for (int k = threadIdx.x; k < HTOT; k += 256) row[k] = src[k];
    __syncthreads();
    // WpT: this source row is A-row cp -> rt = cp>>4, row15 = cp&15
    {
      int rt = cp >> 4, rl = cp & 15;
      f16* dwp = WpT + (size_t)(L * 80 + rt) * 40 * 512;
      for (int xp = threadIdx.x; xp < HTOT; xp += 256) {
        int j_i = xp / HC, ch_i = xp % HC;
        f16 v = (f16)((j_i <= j_o) ? row[ch_i * NS + j_i] : 0.0f);
        int ks = xp >> 5, q = (xp >> 3) & 3, e = xp & 7;
        dwp[ks * 512 + (q * 16 + rl) * 8 + e] = v;
      }
    }
    // WsT: A-row ch_o of spin j_o, cols relative to block base HC*(j_o&~7)
    {
      int base = HC * (j_o & ~7);
      int tile = ch_o >> 4, tl = ch_o & 15;
      f16* dws = WsT + (size_t)(((L * NS + j_o) * 2 + tile) * 5) * 512;
      for (int kr = threadIdx.x; kr < 160; kr += 256) {
        int xp = base + kr;
        int j_i = xp / HC, ch_i = xp % HC;
        f16 v = (f16)((j_i <= j_o) ? row[ch_i * NS + j_i] : 0.0f);
        int ks = kr >> 5, q = (kr >> 3) & 3, e = kr & 7;
        dws[ks * 512 + (q * 16 + tl) * 8 + e] = v;
      }
      if (ch_o < 12) {  // zero pad rows ch=20..31 (tile1 rows 4..15)
        int zl = (20 + ch_o) & 15;
        f16* dz = WsT + (size_t)(((L * NS + j_o) * 2 + 1) * 5) * 512;
        for (int kr = threadIdx.x; kr < 160; kr += 256) {
          int ks = kr >> 5, q = (kr >> 3) & 3, e = kr & 7;
          dz[ks * 512 + (q * 16 + zl) * 8 + e] = (f16)0.0f;
        }
      }
    }
  } else if (bid < 4 * HTOT + NS) {
    int j_o = bid - 4 * HTOT;
    for (int idx = threadIdx.x; idx < 32 * 64; idx += 256) {
      int ch = idx >> 6, c = idx & 63;
      float v = (ch < HC && c < j_o) ? W1[((size_t)ch * NS + j_o) * NS + c] : 0.0f;
      int tile = ch >> 4, tl = ch & 15, ks = c >> 5, q = (c >> 3) & 3, e = c & 7;
      W1T[(size_t)((j_o * 2 + tile) * 2 + ks) * 512 + (q * 16 + tl) * 8 + e] = (f16)v;
    }
  } else if (bid < 4 * HTOT + NS + 8) {
    int m = bid - (4 * HTOT + NS);
    int I = m * KB;
    for (int idx = threadIdx.x; idx < 8 * 16 * 32; idx += 256) {
      int t = idx >> 9, tp = (idx >> 5) & 15, k = idx & 31;
      float v = (tp < 8 && k < HC && t <= tp)
                    ? W6[(size_t)(I + tp) * HTOT + k * NS + (I + t)]
                    : 0.0f;
      int q = k >> 3, e = k & 7;
      W6bT[(size_t)(m * 8 + t) * 512 + (q * 16 + tp) * 8 + e] = (f16)v;
    }
  } else {
    int m = bid - (4 * HTOT + NS + 8);
    int I = m * KB;
    for (int idx = threadIdx.x; idx < 16 * HTOT; idx += 256) {
      int tp = idx / HTOT, xp = idx % HTOT;
      int j_i = xp / HC, ch_i = xp % HC;
      float v = (tp < 8 && j_i <= I + tp)
                    ? W6[(size_t)(I + tp) * HTOT + ch_i * NS + j_i]
                    : 0.0f;
      int ks = xp >> 5, q = (xp >> 3) & 3, e = xp & 7;
      W6T[(size_t)(m * 40 + ks) * 512 + (q * 16 + tp) * 8 + e] = (f16)v;
    }
  }
}

// ---------------------------------------------------------------------------
// gemm_hist: history GEMMs for block starting at spin I, all 5 layer-slots.
//  L<4 : Zg[L][c][b]  = sum_{k<20I} W(L)[20I+c][k] * AH[L][k][b], c=0..159
//  L==4: Zg6[tp][b]   = sum_{k<20I} W6row(tp)[k]   * AH[4][k][b], tp=0..15
// MFMA f32_16x16x32_f16. A loads coalesced from fragment-order WpT/W6T;
// AH [L][g=k/8][b][e=k%8] is the raw B-fragment layout.
// ---------------------------------------------------------------------------
__global__ __launch_bounds__(256) void gemm_hist(
    const f16* __restrict__ WpT, const f16* __restrict__ W6T,
    const f16* __restrict__ AH, float* __restrict__ Zg,
    float* __restrict__ Zg6, int I, int BS) {
  const int L = blockIdx.y;
  const int tid = threadIdx.x;
  const int lane = tid & 63;
  const int w = tid >> 6;
  const int l15 = tid & 15;
  const int quad = lane >> 4;
  const int m = I >> 3;
  const int G32 = (HC * I) >> 5;

  if (L == 4) {
    const int b0 = blockIdx.x * 64 + w * 16;
    f32x4 acc = (f32x4){0.f, 0.f, 0.f, 0.f};
    const f16* ap = W6T + (size_t)(m * 40) * 512 + lane * 8;
    const f16* bp = AH + ((size_t)(4 * 160 + quad) * BS + b0 + l15) * 8;
#pragma unroll 2
    for (int ks = 0; ks < G32; ++ks) {
      f16x8 af = *(const f16x8*)ap;
      f16x8 bf = *(const f16x8*)bp;
      acc = __builtin_amdgcn_mfma_f32_16x16x32_f16(af, bf, acc, 0, 0, 0);
      ap += 512;
      bp += (size_t)4 * BS * 8;
    }
#pragma unroll
    for (int r = 0; r < 4; ++r)
      Zg6[(size_t)(quad * 4 + r) * BS + b0 + l15] = acc[r];
    return;
  }

  const int wm = w & 1, wn = w >> 1;
  const int b0 = blockIdx.x * 64 + wn * 32;

  f32x4 acc[5][2];
#pragma unroll
  for (int mt = 0; mt < 5; ++mt) {
    acc[mt][0] = (f32x4){0.f, 0.f, 0.f, 0.f};
    acc[mt][1] = (f32x4){0.f, 0.f, 0.f, 0.f};
  }

  const f16* ap = WpT + (size_t)((L * 80 + 10 * m + 5 * wm) * 40) * 512 + lane * 8;
  const f16* bp = AH + ((size_t)(L * 160 + quad) * BS + b0 + l15) * 8;

#pragma unroll 2
  for (int ks = 0; ks < G32; ++ks) {
    f16x8 bf0 = *(const f16x8*)(bp);
    f16x8 bf1 = *(const f16x8*)(bp + 128);
    f16x8 af[5];
#pragma unroll
    for (int mt = 0; mt < 5; ++mt)
      af[mt] = *(const f16x8*)(ap + (size_t)mt * 40 * 512);
#pragma unroll
    for (int mt = 0; mt < 5; ++mt) {
      acc[mt][0] = __builtin_amdgcn_mfma_f32_16x16x32_f16(af[mt], bf0, acc[mt][0], 0, 0, 0);
      acc[mt][1] = __builtin_amdgcn_mfma_f32_16x16x32_f16(af[mt], bf1, acc[mt][1], 0, 0, 0);
    }
    ap += 512;
    bp += (size_t)4 * BS * 8;
  }

#pragma unroll
  for (int mt = 0; mt < 5; ++mt)
#pragma unroll
    for (int nt = 0; nt < 2; ++nt)
#pragma unroll
      for (int r = 0; r < 4; ++r) {
        int c = wm * 80 + mt * 16 + quad * 4 + r;
        int b = b0 + nt * 16 + l15;
        Zg[(size_t)(L * 160 + c) * BS + b] = acc[mt][nt][r];
      }
}

// ---------------------------------------------------------------------------
// seq_block v6 (MFMA phases, coalesced A): 1 wave, BT=16 batch rows = MFMA N dim.
// Per t: L1 = 2 tiles x <=2 K-steps; layers 2..5 = 2 tiles x <=5 K-steps each,
// init from Zg; z6 = 1 MFMA/t into persistent acc6 (init from Zg6). Fragment
// mappings mirror gemm_hist (A: lane-contiguous fragment order; B: col=l15;
// C: col=l15, row=quad*4+reg). All K roundup slop = zero-weights x zero-acts.
// ---------------------------------------------------------------------------
__global__ __launch_bounds__(64) void seq_block(
    const f16* __restrict__ WsT, const f16* __restrict__ W1T,
    const f16* __restrict__ W6bT, f16* __restrict__ AH,
    const float* __restrict__ Zg, const float* __restrict__ Zg6,
    f16* __restrict__ s_ws, const float* __restrict__ u,
    float* __restrict__ outp, int I, int BS, int b0) {
  __shared__ __align__(16) f16 aL[5][BT][184];   // 29440 B (184: 2-way-free banks)
  __shared__ __align__(16) f16 sL[BT][72];       // 2304 B -> 31744 B total

  const int lane = threadIdx.x;
  const int l15 = lane & 15;            // MFMA col = batch row in WG
  const int quad = lane >> 4;           // MFMA k-group / C row-group
  const int m = I >> 3;
  const int bcol = blockIdx.x * BT + l15;
  const int bg = b0 + bcol;

  // zero LDS (masked-weight / K-pad tails must read as 0)
  {
    f16x8 z = {};
    f16x8* pa = (f16x8*)&aL[0][0][0];
    for (int k = lane; k < (5 * BT * 184) / 8; k += 64) pa[k] = z;
    f16x8* ps = (f16x8*)&sL[0][0];
    for (int k = lane; k < (BT * 72) / 8; k += 64) ps[k] = z;
  }
  __syncthreads();

  // load sampled-bit history j < I
  for (int c8 = quad; c8 < (I >> 3); c8 += 4) {
    f16x8 v = *(const f16x8*)(s_ws + (size_t)(blockIdx.x * BT + l15) * NS + c8 * 8);
    *(f16x8*)&sL[l15][c8 * 8] = v;
  }

  // z6 accumulator: C rows = tp (quad*4+r), cols = batch (l15); init from history
  f32x4 acc6;
#pragma unroll
  for (int r = 0; r < 4; ++r)
    acc6[r] = Zg6[(size_t)(quad * 4 + r) * BS + bcol];
  __syncthreads();

  for (int t = 0; t < KB; ++t) {
    const int i = I + t;

    // ---- layer 1: z[32ch x 16b] = W1(i) (32x64) . sL (64x16) ----
    {
      f32x4 z0 = (f32x4){0.f, 0.f, 0.f, 0.f};
      f32x4 z1 = (f32x4){0.f, 0.f, 0.f, 0.f};
      const int KS1 = (i + 31) >> 5;
      const f16* w0 = W1T + (size_t)(i * 2) * 2 * 512 + lane * 8;
      for (int ks = 0; ks < KS1; ++ks) {
        f16x8 bf = *(const f16x8*)&sL[l15][quad * 8 + 32 * ks];
        f16x8 a0 = *(const f16x8*)(w0 + ks * 512);
        f16x8 a1 = *(const f16x8*)(w0 + (2 + ks) * 512);
        z0 = __builtin_amdgcn_mfma_f32_16x16x32_f16(a0, bf, z0, 0, 0, 0);
        z1 = __builtin_amdgcn_mfma_f32_16x16x32_f16(a1, bf, z1, 0, 0, 0);
      }
      f16x4 o0;
#pragma unroll
      for (int r = 0; r < 4; ++r) o0[r] = (f16)sigm(z0[r]);
      *(f16x4*)&aL[0][l15][t * HC + quad * 4] = o0;
      if (quad == 0) {
        f16x4 o1;
#pragma unroll
        for (int r = 0; r < 4; ++r) o1[r] = (f16)sigm(z1[r]);
        *(f16x4*)&aL[0][l15][t * HC + 16] = o1;
      }
    }
    __syncthreads();

    // ---- layers 2..5: z = Zg-init + W(L,i) (32xK) . aL[L] (Kx16) ----
    const int KS = (HC * (t + 1) + 31) >> 5;
    for (int L = 0; L < 4; ++L) {
      f32x4 z0, z1;
#pragma unroll
      for (int r = 0; r < 4; ++r) {
        z0[r] = Zg[(size_t)(L * 160 + t * HC + quad * 4 + r) * BS + bcol];
        z1[r] = 0.f;
      }
      if (quad == 0) {
#pragma unroll
        for (int r = 0; r < 4; ++r)
          z1[r] = Zg[(size_t)(L * 160 + t * HC + 16 + r) * BS + bcol];
      }
      const f16* wb = WsT + (size_t)((L * NS + i) * 2) * 5 * 512 + lane * 8;
      for (int ks = 0; ks < KS; ++ks) {
        f16x8 bf = *(const f16x8*)&aL[L][l15][quad * 8 + 32 * ks];
        f16x8 a0 = *(const f16x8*)(wb + ks * 512);
        f16x8 a1 = *(const f16x8*)(wb + (5 + ks) * 512);
        z0 = __builtin_amdgcn_mfma_f32_16x16x32_f16(a0, bf, z0, 0, 0, 0);
        z1 = __builtin_amdgcn_mfma_f32_16x16x32_f16(a1, bf, z1, 0, 0, 0);
      }
      f16x4 o0;
#pragma unroll
      for (int r = 0; r < 4; ++r) o0[r] = (f16)sigm(z0[r]);
      *(f16x4*)&aL[L + 1][l15][t * HC + quad * 4] = o0;
      if (quad == 0) {
        f16x4 o1;
#pragma unroll
        for (int r = 0; r < 4; ++r) o1[r] = (f16)sigm(z1[r]);
        *(f16x4*)&aL[L + 1][l15][t * HC + 16] = o1;
      }
      __syncthreads();
    }

    // ---- z6: one MFMA accumulating a5(spin i) into all tp rows (W6bT masks) ----
    {
      f16x8 b5 = *(const f16x8*)&aL[4][l15][t * HC + quad * 8];
      f16x8 a6 = *(const f16x8*)(W6bT + (size_t)(m * 8 + t) * 512 + lane * 8);
      acc6 = __builtin_amdgcn_mfma_f32_16x16x32_f16(a6, b5, acc6, 0, 0, 0);
      if (quad == (t >> 2)) {
        int r3 = t & 3;
        float v = r3 == 0 ? acc6[0] : r3 == 1 ? acc6[1] : r3 == 2 ? acc6[2] : acc6[3];
        float x = sigm(v);
        outp[(size_t)bg * NS + i] = x;  // final output col i == sampling-time x
        float uu = u[(size_t)i * NB + bg];
        sL[l15][i] = (f16)((x >= uu) ? 1.0f : -1.0f);
      }
    }
    __syncthreads();
  }

  // ---- bulk writeout: block activations -> global AH ([L][g][b][e]), s bits ----
  for (int w = lane; w < 5 * 20 * BT; w += 64) {
    int rr = w & 15;
    int q = w >> 4;            // 0..99
    int L = q / 20, x8 = q % 20;
    f16x8 v = *(const f16x8*)&aL[L][rr][x8 * 8];
    int gg = ((HC * I) >> 3) + x8;
    *(f16x8*)(AH + ((size_t)(L * 160 + gg) * BS + blockIdx.x * BT + rr) * 8) = v;
  }
  if (lane < BT) {
    *(f16x8*)(s_ws + (size_t)(blockIdx.x * BT + lane) * NS + I) =
        *(const f16x8*)&sL[lane][I];
  }
}

// ---------------------------------------------------------------------------
extern "C" void kernel_launch(void* const* d_in, const int* in_sizes, int n_in,
                              void* d_out, int out_size, void* d_ws, size_t ws_size,
                              hipStream_t stream) {
  (void)in_sizes; (void)n_in; (void)out_size;
  const float* u  = (const float*)d_in[1];
  const float* W1 = (const float*)d_in[2];
  const float* W2 = (const float*)d_in[3];
  const float* W3 = (const float*)d_in[4];
  const float* W4 = (const float*)d_in[5];
  const float* W5 = (const float*)d_in[6];
  const float* W6 = (const float*)d_in[7];
  float* outp = (float*)d_out;

  const size_t wpTEls  = (size_t)4 * 80 * 40 * 512;      // 6.55M  hist A
  const size_t wsTEls  = (size_t)4 * NS * 2 * 5 * 512;   // 1.31M  seq A
  const size_t w1TEls  = (size_t)NS * 2 * 2 * 512;       // 131K   seq L1 A
  const size_t w6bTEls = (size_t)64 * 512;               // 33K    seq z6 A
  const size_t w6TEls  = (size_t)8 * 40 * 512;           // 164K   hist z6 A
  const size_t wEls = wpTEls + wsTEls + w1TEls + w6bTEls + w6TEls;
  const size_t wBytes = wEls * sizeof(f16);

  // per-batch-row workspace: AH 5*160*8*2 + Zg 4*160*4 + Zg6 16*4 + s_ws 64*2
  size_t rem = (ws_size > wBytes + 4096) ? (ws_size - wBytes - 4096) : 0;
  long long bs = (long long)(rem / 15552);
  bs = (bs / 64) * 64;
  if (bs > NB) bs = NB;
  if (bs < 64) bs = 64;
  const int BS = (int)bs;

  f16* WpT   = (f16*)d_ws;
  f16* WsT   = WpT + wpTEls;
  f16* W1T   = WsT + wsTEls;
  f16* W6bT  = W1T + w1TEls;
  f16* W6T   = W6bT + w6bTEls;
  f16* AH    = W6T + w6TEls;
  float* Zg  = (float*)(AH + (size_t)5 * 160 * BS * 8);
  float* Zg6 = Zg + (size_t)4 * 160 * BS;
  f16* s_ws  = (f16*)(Zg6 + (size_t)16 * BS);

  prep<<<dim3(4 * HTOT + NS + 16), dim3(256), 0, stream>>>(
      W1, W2, W3, W4, W5, W6, WpT, WsT, W1T, W6bT, W6T);

  for (int c0 = 0; c0 < NB; c0 += BS) {
    int nr = NB - c0; if (nr > BS) nr = BS;
    for (int m = 0; m < NS / KB; ++m) {
      const int I = m * KB;
      gemm_hist<<<dim3(nr / 64, 5), dim3(256), 0, stream>>>(
          WpT, W6T, AH, Zg, Zg6, I, BS);
      seq_block<<<dim3(nr / BT), dim3(64), 0, stream>>>(
          WsT, W1T, W6bT, AH, Zg, Zg6, s_ws, u, outp, I, BS, c0);
    }
  }
}

// Round 5
// 1154.156 us; speedup vs baseline: 1.3840x; 1.1715x over previous
//
#include <hip/hip_runtime.h>

// Autoregressive masked net sampler.
//  - output col i == sampling-time x[:,i]  (masks: out i depends on spins < i only)
//  - spin blocks of KB=8: history part = dense GEMM (MFMA f16), intra-block part
//    sequential per-row (rows independent -> no grid sync).
// R7: seq phases -> MFMA. R8: all MFMA A-operands pre-swizzled to fragment order
//     (coalesced 1KB wave-reads); z6 merged into gemm_hist. seq 115->64us, FETCH ==
//     Zg+u exactly. Profile: occ 10% = 1 wave/SIMD exactly -> wall == serial chain,
//     3200 cy/phase: Zg L3 latency + L2 weight latency + LDS roundtrip all exposed.
// R9 (this): latency off the chain, same structure:
//     - Zg -> post-add; all 4 layers' Zg issued at top of each t (overlaps phases)
//     - full unroll t-loop (KS compile-time; loads hoist across waitcnt-syncs)
//     - u pre-loaded into 8 regs
//     - z6 B-operand = fresh a5 only (W6bT masks k>=20) -> build via 6 shfls from
//       layer-5 C-regs; no post-L5 barrier, no z6 LDS read
//     - sampled bit carried in reg, patched into t+1 L1 B-frag (static elem under
//       unroll); no end-of-t barrier.  Barriers/t: 6 -> 4.

#define NS   64          // spins
#define HC   20          // hidden channels per spin
#define HTOT 1280        // NS*HC
#define NB   16384       // batch
#define KB   8           // spins per block (8 blocks)
#define BT   16          // batch rows per seq workgroup (MFMA N-tile)

typedef _Float16 f16;
typedef _Float16 f16x2 __attribute__((ext_vector_type(2)));
typedef _Float16 f16x4 __attribute__((ext_vector_type(4)));
typedef _Float16 f16x8 __attribute__((ext_vector_type(8)));
typedef float f32x4 __attribute__((ext_vector_type(4)));
typedef unsigned int u32x4 __attribute__((ext_vector_type(4)));

static __device__ __forceinline__ float sigm(float z) {
  return __builtin_amdgcn_rcpf(1.0f + __expf(-z));
}

static __device__ __forceinline__ unsigned pk2(float a, float b) {
  f16x2 t;
  t[0] = (f16)a;
  t[1] = (f16)b;
  return __builtin_bit_cast(unsigned, t);
}

// ---------------------------------------------------------------------------
// prep: build masked f16 weights, pre-swizzled to MFMA A-fragment order.
// Fragment order: lane = quad*16 + row15, elems 8; col = ks*32 + quad*8 + e.
//  WpT [L][rt=row/16][ks=0..39][512]   row=j_o*20+ch_o, mask j_i<=j_o (hist A)
//  WsT [L][i][tile=ch/16][ks=0..4][512] cols rel to HC*(i&~7), ch padded ->32 (seq A)
//  W1T [i][tile][ks=0..1][512]          cols = spins, mask c<i (seq L1 A)
//  W6bT[m*8+t][512]                     16 tp rows x 32 k, mask t<=tp,k<20 (z6 MFMA A)
//  W6T [m][ks=0..39][512]               16 tp rows (8 real), mask j_i<=I+tp (z6 hist A)
// ---------------------------------------------------------------------------
__global__ __launch_bounds__(256) void prep(
    const float* __restrict__ W1, const float* __restrict__ W2,
    const float* __restrict__ W3, const float* __restrict__ W4,
    const float* __restrict__ W5, const float* __restrict__ W6,
    f16* __restrict__ WpT, f16* __restrict__ WsT, f16* __restrict__ W1T,
    f16* __restrict__ W6bT, f16* __restrict__ W6T) {
  __shared__ float row[HTOT];
  int bid = blockIdx.x;
  if (bid < 4 * HTOT) {
    int L = bid / HTOT, cp = bid % HTOT;
    int j_o = cp / HC, ch_o = cp % HC;
    const float* Wsrc = (L == 0) ? W2 : (L == 1) ? W3 : (L == 2) ? W4 : W5;
    const float* src = Wsrc + (size_t)(ch_o * NS + j_o) * HTOT;
    for (int k = threadIdx.x; k < HTOT; k += 256) row[k] = src[k];
    __syncthreads();
    // WpT: this source row is A-row cp -> rt = cp>>4, row15 = cp&15
    {
      int rt = cp >> 4, rl = cp & 15;
      f16* dwp = WpT + (size_t)(L * 80 + rt) * 40 * 512;
      for (int xp = threadIdx.x; xp < HTOT; xp += 256) {
        int j_i = xp / HC, ch_i = xp % HC;
        f16 v = (f16)((j_i <= j_o) ? row[ch_i * NS + j_i] : 0.0f);
        int ks = xp >> 5, q = (xp >> 3) & 3, e = xp & 7;
        dwp[ks * 512 + (q * 16 + rl) * 8 + e] = v;
      }
    }
    // WsT: A-row ch_o of spin j_o, cols relative to block base HC*(j_o&~7)
    {
      int base = HC * (j_o & ~7);
      int tile = ch_o >> 4, tl = ch_o & 15;
      f16* dws = WsT + (size_t)(((L * NS + j_o) * 2 + tile) * 5) * 512;
      for (int kr = threadIdx.x; kr < 160; kr += 256) {
        int xp = base + kr;
        int j_i = xp / HC, ch_i = xp % HC;
        f16 v = (f16)((j_i <= j_o) ? row[ch_i * NS + j_i] : 0.0f);
        int ks = kr >> 5, q = (kr >> 3) & 3, e = kr & 7;
        dws[ks * 512 + (q * 16 + tl) * 8 + e] = v;
      }
      if (ch_o < 12) {  // zero pad rows ch=20..31 (tile1 rows 4..15)
        int zl = (20 + ch_o) & 15;
        f16* dz = WsT + (size_t)(((L * NS + j_o) * 2 + 1) * 5) * 512;
        for (int kr = threadIdx.x; kr < 160; kr += 256) {
          int ks = kr >> 5, q = (kr >> 3) & 3, e = kr & 7;
          dz[ks * 512 + (q * 16 + zl) * 8 + e] = (f16)0.0f;
        }
      }
    }
  } else if (bid < 4 * HTOT + NS) {
    int j_o = bid - 4 * HTOT;
    for (int idx = threadIdx.x; idx < 32 * 64; idx += 256) {
      int ch = idx >> 6, c = idx & 63;
      float v = (ch < HC && c < j_o) ? W1[((size_t)ch * NS + j_o) * NS + c] : 0.0f;
      int tile = ch >> 4, tl = ch & 15, ks = c >> 5, q = (c >> 3) & 3, e = c & 7;
      W1T[(size_t)((j_o * 2 + tile) * 2 + ks) * 512 + (q * 16 + tl) * 8 + e] = (f16)v;
    }
  } else if (bid < 4 * HTOT + NS + 8) {
    int m = bid - (4 * HTOT + NS);
    int I = m * KB;
    for (int idx = threadIdx.x; idx < 8 * 16 * 32; idx += 256) {
      int t = idx >> 9, tp = (idx >> 5) & 15, k = idx & 31;
      float v = (tp < 8 && k < HC && t <= tp)
                    ? W6[(size_t)(I + tp) * HTOT + k * NS + (I + t)]
                    : 0.0f;
      int q = k >> 3, e = k & 7;
      W6bT[(size_t)(m * 8 + t) * 512 + (q * 16 + tp) * 8 + e] = (f16)v;
    }
  } else {
    int m = bid - (4 * HTOT + NS + 8);
    int I = m * KB;
    for (int idx = threadIdx.x; idx < 16 * HTOT; idx += 256) {
      int tp = idx / HTOT, xp = idx % HTOT;
      int j_i = xp / HC, ch_i = xp % HC;
      float v = (tp < 8 && j_i <= I + tp)
                    ? W6[(size_t)(I + tp) * HTOT + ch_i * NS + j_i]
                    : 0.0f;
      int ks = xp >> 5, q = (xp >> 3) & 3, e = xp & 7;
      W6T[(size_t)(m * 40 + ks) * 512 + (q * 16 + tp) * 8 + e] = (f16)v;
    }
  }
}

// ---------------------------------------------------------------------------
// gemm_hist: history GEMMs for block starting at spin I, all 5 layer-slots.
//  L<4 : Zg[L][c][b]  = sum_{k<20I} W(L)[20I+c][k] * AH[L][k][b], c=0..159
//  L==4: Zg6[tp][b]   = sum_{k<20I} W6row(tp)[k]   * AH[4][k][b], tp=0..15
// MFMA f32_16x16x32_f16. A loads coalesced from fragment-order WpT/W6T;
// AH [L][g=k/8][b][e=k%8] is the raw B-fragment layout.
// ---------------------------------------------------------------------------
__global__ __launch_bounds__(256) void gemm_hist(
    const f16* __restrict__ WpT, const f16* __restrict__ W6T,
    const f16* __restrict__ AH, float* __restrict__ Zg,
    float* __restrict__ Zg6, int I, int BS) {
  const int L = blockIdx.y;
  const int tid = threadIdx.x;
  const int lane = tid & 63;
  const int w = tid >> 6;
  const int l15 = tid & 15;
  const int quad = lane >> 4;
  const int m = I >> 3;
  const int G32 = (HC * I) >> 5;

  if (L == 4) {
    const int b0 = blockIdx.x * 64 + w * 16;
    f32x4 acc = (f32x4){0.f, 0.f, 0.f, 0.f};
    const f16* ap = W6T + (size_t)(m * 40) * 512 + lane * 8;
    const f16* bp = AH + ((size_t)(4 * 160 + quad) * BS + b0 + l15) * 8;
#pragma unroll 2
    for (int ks = 0; ks < G32; ++ks) {
      f16x8 af = *(const f16x8*)ap;
      f16x8 bf = *(const f16x8*)bp;
      acc = __builtin_amdgcn_mfma_f32_16x16x32_f16(af, bf, acc, 0, 0, 0);
      ap += 512;
      bp += (size_t)4 * BS * 8;
    }
#pragma unroll
    for (int r = 0; r < 4; ++r)
      Zg6[(size_t)(quad * 4 + r) * BS + b0 + l15] = acc[r];
    return;
  }

  const int wm = w & 1, wn = w >> 1;
  const int b0 = blockIdx.x * 64 + wn * 32;

  f32x4 acc[5][2];
#pragma unroll
  for (int mt = 0; mt < 5; ++mt) {
    acc[mt][0] = (f32x4){0.f, 0.f, 0.f, 0.f};
    acc[mt][1] = (f32x4){0.f, 0.f, 0.f, 0.f};
  }

  const f16* ap = WpT + (size_t)((L * 80 + 10 * m + 5 * wm) * 40) * 512 + lane * 8;
  const f16* bp = AH + ((size_t)(L * 160 + quad) * BS + b0 + l15) * 8;

#pragma unroll 2
  for (int ks = 0; ks < G32; ++ks) {
    f16x8 bf0 = *(const f16x8*)(bp);
    f16x8 bf1 = *(const f16x8*)(bp + 128);
    f16x8 af[5];
#pragma unroll
    for (int mt = 0; mt < 5; ++mt)
      af[mt] = *(const f16x8*)(ap + (size_t)mt * 40 * 512);
#pragma unroll
    for (int mt = 0; mt < 5; ++mt) {
      acc[mt][0] = __builtin_amdgcn_mfma_f32_16x16x32_f16(af[mt], bf0, acc[mt][0], 0, 0, 0);
      acc[mt][1] = __builtin_amdgcn_mfma_f32_16x16x32_f16(af[mt], bf1, acc[mt][1], 0, 0, 0);
    }
    ap += 512;
    bp += (size_t)4 * BS * 8;
  }

#pragma unroll
  for (int mt = 0; mt < 5; ++mt)
#pragma unroll
    for (int nt = 0; nt < 2; ++nt)
#pragma unroll
      for (int r = 0; r < 4; ++r) {
        int c = wm * 80 + mt * 16 + quad * 4 + r;
        int b = b0 + nt * 16 + l15;
        Zg[(size_t)(L * 160 + c) * BS + b] = acc[mt][nt][r];
      }
}

// ---------------------------------------------------------------------------
// seq_block v7 (latency-pipelined MFMA phases): 1 wave, BT=16 batch rows.
// Full t-unroll; Zg post-added (loads issued at t start); u preloaded; z6 via
// shfl from layer-5 C-regs (no barrier, no LDS); sampled bit carried in reg and
// patched into next t's L1 B-frag. 4 syncs per t (after L1..L4 writes).
// ---------------------------------------------------------------------------
__global__ __launch_bounds__(64) void seq_block(
    const f16* __restrict__ WsT, const f16* __restrict__ W1T,
    const f16* __restrict__ W6bT, f16* __restrict__ AH,
    const float* __restrict__ Zg, const float* __restrict__ Zg6,
    f16* __restrict__ s_ws, const float* __restrict__ u,
    float* __restrict__ outp, int I, int BS, int b0) {
  __shared__ __align__(16) f16 aL[5][BT][184];   // 29440 B
  __shared__ __align__(16) f16 sL[BT][72];       // 2304 B -> 31744 B total

  const int lane = threadIdx.x;
  const int l15 = lane & 15;            // MFMA col = batch row in WG
  const int quad = lane >> 4;           // MFMA k-group / C row-group
  const int m = I >> 3;
  const int bcol = blockIdx.x * BT + l15;
  const int bg = b0 + bcol;

  // early global loads: u for all 8 spins, z6 history accumulator
  float uv[KB];
#pragma unroll
  for (int t = 0; t < KB; ++t) uv[t] = u[(size_t)(I + t) * NB + bg];
  f32x4 acc6;
#pragma unroll
  for (int r = 0; r < 4; ++r)
    acc6[r] = Zg6[(size_t)(quad * 4 + r) * BS + bcol];

  // zero LDS (masked-weight / K-pad tails must read as 0)
  {
    f16x8 z = {};
    f16x8* pa = (f16x8*)&aL[0][0][0];
    for (int k = lane; k < (5 * BT * 184) / 8; k += 64) pa[k] = z;
    f16x8* ps = (f16x8*)&sL[0][0];
    for (int k = lane; k < (BT * 72) / 8; k += 64) ps[k] = z;
  }
  __syncthreads();

  // load sampled-bit history j < I
  for (int c8 = quad; c8 < (I >> 3); c8 += 4) {
    f16x8 v = *(const f16x8*)(s_ws + (size_t)(blockIdx.x * BT + l15) * NS + c8 * 8);
    *(f16x8*)&sL[l15][c8 * 8] = v;
  }
  __syncthreads();

  float bitv = 0.0f;  // freshest sampled bit (spin I+t-1), per batch-column

#pragma unroll
  for (int t = 0; t < KB; ++t) {
    const int i = I + t;

    // ---- prefetch this t's Zg rows for all 4 hidden layers (post-added) ----
    float zg0[4][4], zg1[4][4];
#pragma unroll
    for (int L = 0; L < 4; ++L)
#pragma unroll
      for (int r = 0; r < 4; ++r) {
        zg0[L][r] = Zg[(size_t)(L * 160 + t * HC + quad * 4 + r) * BS + bcol];
        zg1[L][r] =
            (quad == 0) ? Zg[(size_t)(L * 160 + t * HC + 16 + r) * BS + bcol] : 0.f;
      }

    // ---- layer 1: z[32ch x 16b] = W1(i) (32x64) . sL (64x16) ----
    {
      f32x4 z0 = (f32x4){0.f, 0.f, 0.f, 0.f};
      f32x4 z1 = (f32x4){0.f, 0.f, 0.f, 0.f};
      const int KS1 = (i + 31) >> 5;
      const f16* w0 = W1T + (size_t)(i * 2) * 2 * 512 + lane * 8;
      for (int ks = 0; ks < KS1; ++ks) {
        f16x8 bf = *(const f16x8*)&sL[l15][quad * 8 + 32 * ks];
        if (t > 0 && ks == ((i - 1) >> 5) && quad == (((I & 31) + t - 1) >> 3))
          bf[(t - 1) & 7] = (f16)bitv;  // freshest bit, not yet barrier-visible
        f16x8 a0 = *(const f16x8*)(w0 + ks * 512);
        f16x8 a1 = *(const f16x8*)(w0 + (2 + ks) * 512);
        z0 = __builtin_amdgcn_mfma_f32_16x16x32_f16(a0, bf, z0, 0, 0, 0);
        z1 = __builtin_amdgcn_mfma_f32_16x16x32_f16(a1, bf, z1, 0, 0, 0);
      }
      f16x4 o0;
#pragma unroll
      for (int r = 0; r < 4; ++r) o0[r] = (f16)sigm(z0[r]);
      *(f16x4*)&aL[0][l15][t * HC + quad * 4] = o0;
      if (quad == 0) {
        f16x4 o1;
#pragma unroll
        for (int r = 0; r < 4; ++r) o1[r] = (f16)sigm(z1[r]);
        *(f16x4*)&aL[0][l15][t * HC + 16] = o1;
      }
    }
    __syncthreads();

    // ---- layers 2..5: z = W(L,i) (32xK) . aL[L] (Kx16), then += Zg ----
    const int KS = (HC * (t + 1) + 31) >> 5;  // compile-time under unroll
    float a5o0[4], a5o1[4];
#pragma unroll
    for (int L = 0; L < 4; ++L) {
      f32x4 z0 = (f32x4){0.f, 0.f, 0.f, 0.f};
      f32x4 z1 = (f32x4){0.f, 0.f, 0.f, 0.f};
      const f16* wb = WsT + (size_t)((L * NS + i) * 2) * 5 * 512 + lane * 8;
#pragma unroll
      for (int ks = 0; ks < KS; ++ks) {
        f16x8 bf = *(const f16x8*)&aL[L][l15][quad * 8 + 32 * ks];
        f16x8 a0 = *(const f16x8*)(wb + ks * 512);
        f16x8 a1 = *(const f16x8*)(wb + (5 + ks) * 512);
        z0 = __builtin_amdgcn_mfma_f32_16x16x32_f16(a0, bf, z0, 0, 0, 0);
        z1 = __builtin_amdgcn_mfma_f32_16x16x32_f16(a1, bf, z1, 0, 0, 0);
      }
      f16x4 o0;
#pragma unroll
      for (int r = 0; r < 4; ++r) {
        float v = sigm(z0[r] + zg0[L][r]);
        o0[r] = (f16)v;
        if (L == 3) a5o0[r] = v;
      }
      *(f16x4*)&aL[L + 1][l15][t * HC + quad * 4] = o0;
      {
        f16x4 o1;
#pragma unroll
        for (int r = 0; r < 4; ++r) {
          float v = sigm(z1[r] + zg1[L][r]);
          o1[r] = (f16)v;
          if (L == 3) a5o1[r] = v;
        }
        if (quad == 0) *(f16x4*)&aL[L + 1][l15][t * HC + 16] = o1;
      }
      if (L < 3) __syncthreads();  // aL[4] never cross-read before writeout
    }

    // ---- z6: B-frag = fresh a5 only (W6bT zero-masks k>=20) via shfl ----
    {
      unsigned p0 = pk2(a5o0[0], a5o0[1]);
      unsigned p1 = pk2(a5o0[2], a5o0[3]);
      unsigned p2 = pk2(a5o1[0], a5o1[1]);
      unsigned p3 = pk2(a5o1[2], a5o1[3]);
      int src1 = (((quad * 2) & 3) << 4) + l15;
      int src2 = src1 + 16;
      unsigned d0 = (unsigned)__shfl((int)p0, src1, 64);
      unsigned d1 = (unsigned)__shfl((int)p1, src1, 64);
      unsigned d2 = (unsigned)__shfl((int)p0, src2, 64);
      unsigned d3 = (unsigned)__shfl((int)p1, src2, 64);
      unsigned e0 = (unsigned)__shfl((int)p2, src1, 64);
      unsigned e1 = (unsigned)__shfl((int)p3, src1, 64);
      u32x4 bv = (quad < 2) ? (u32x4){d0, d1, d2, d3} : (u32x4){e0, e1, e0, e1};
      f16x8 b5 = __builtin_bit_cast(f16x8, bv);
      f16x8 a6 = *(const f16x8*)(W6bT + (size_t)(m * 8 + t) * 512 + lane * 8);
      acc6 = __builtin_amdgcn_mfma_f32_16x16x32_f16(a6, b5, acc6, 0, 0, 0);
      // extract row t (owner quad = t>>2, reg t&3; static under unroll)
      float x = sigm(acc6[t & 3]);
      if (quad == (t >> 2)) {
        outp[(size_t)bg * NS + i] = x;  // final output col i == sampling-time x
        sL[l15][i] = (f16)((x >= uv[t]) ? 1.0f : -1.0f);
      }
      float xall = __shfl(x, ((t >> 2) << 4) + l15, 64);
      bitv = (xall >= uv[t]) ? 1.0f : -1.0f;
    }
    // no end-of-t barrier: t+1 L1 gets the fresh bit from bitv; older sL writes
    // are >= 4 waitcnt-syncs old; aL[4] writes only read after the final barrier.
  }
  __syncthreads();

  // ---- bulk writeout: block activations -> global AH ([L][g][b][e]), s bits ----
  for (int w = lane; w < 5 * 20 * BT; w += 64) {
    int rr = w & 15;
    int q = w >> 4;            // 0..99
    int L = q / 20, x8 = q % 20;
    f16x8 v = *(const f16x8*)&aL[L][rr][x8 * 8];
    int gg = ((HC * I) >> 3) + x8;
    *(f16x8*)(AH + ((size_t)(L * 160 + gg) * BS + blockIdx.x * BT + rr) * 8) = v;
  }
  if (lane < BT) {
    *(f16x8*)(s_ws + (size_t)(blockIdx.x * BT + lane) * NS + I) =
        *(const f16x8*)&sL[lane][I];
  }
}

// ---------------------------------------------------------------------------
extern "C" void kernel_launch(void* const* d_in, const int* in_sizes, int n_in,
                              void* d_out, int out_size, void* d_ws, size_t ws_size,
                              hipStream_t stream) {
  (void)in_sizes; (void)n_in; (void)out_size;
  const float* u  = (const float*)d_in[1];
  const float* W1 = (const float*)d_in[2];
  const float* W2 = (const float*)d_in[3];
  const float* W3 = (const float*)d_in[4];
  const float* W4 = (const float*)d_in[5];
  const float* W5 = (const float*)d_in[6];
  const float* W6 = (const float*)d_in[7];
  float* outp = (float*)d_out;

  const size_t wpTEls  = (size_t)4 * 80 * 40 * 512;      // 6.55M  hist A
  const size_t wsTEls  = (size_t)4 * NS * 2 * 5 * 512;   // 1.31M  seq A
  const size_t w1TEls  = (size_t)NS * 2 * 2 * 512;       // 131K   seq L1 A
  const size_t w6bTEls = (size_t)64 * 512;               // 33K    seq z6 A
  const size_t w6TEls  = (size_t)8 * 40 * 512;           // 164K   hist z6 A
  const size_t wEls = wpTEls + wsTEls + w1TEls + w6bTEls + w6TEls;
  const size_t wBytes = wEls * sizeof(f16);

  // per-batch-row workspace: AH 5*160*8*2 + Zg 4*160*4 + Zg6 16*4 + s_ws 64*2
  size_t rem = (ws_size > wBytes + 4096) ? (ws_size - wBytes - 4096) : 0;
  long long bs = (long long)(rem / 15552);
  bs = (bs / 64) * 64;
  if (bs > NB) bs = NB;
  if (bs < 64) bs = 64;
  const int BS = (int)bs;

  f16* WpT   = (f16*)d_ws;
  f16* WsT   = WpT + wpTEls;
  f16* W1T   = WsT + wsTEls;
  f16* W6bT  = W1T + w1TEls;
  f16* W6T   = W6bT + w6bTEls;
  f16* AH    = W6T + w6TEls;
  float* Zg  = (float*)(AH + (size_t)5 * 160 * BS * 8);
  float* Zg6 = Zg + (size_t)4 * 160 * BS;
  f16* s_ws  = (f16*)(Zg6 + (size_t)16 * BS);

  prep<<<dim3(4 * HTOT + NS + 16), dim3(256), 0, stream>>>(
      W1, W2, W3, W4, W5, W6, WpT, WsT, W1T, W6bT, W6T);

  for (int c0 = 0; c0 < NB; c0 += BS) {
    int nr = NB - c0; if (nr > BS) nr = BS;
    for (int m = 0; m < NS / KB; ++m) {
      const int I = m * KB;
      gemm_hist<<<dim3(nr / 64, 5), dim3(256), 0, stream>>>(
          WpT, W6T, AH, Zg, Zg6, I, BS);
      seq_block<<<dim3(nr / BT), dim3(64), 0, stream>>>(
          WsT, W1T, W6bT, AH, Zg, Zg6, s_ws, u, outp, I, BS, c0);
    }
  }
}